// Round 1
// baseline (1157.710 us; speedup 1.0000x reference)
//
#include <hip/hip_runtime.h>

#define N_NODES 50000
#define N_EDGES 800000
#define IN_FEATS 256
#define HIDDEN 64
#define OUTF 32

// ---------------- degree / norm ----------------
__global__ __launch_bounds__(256) void deg_kernel(const int* __restrict__ src,
                                                  const int* __restrict__ dst,
                                                  float* __restrict__ deg_out,
                                                  float* __restrict__ deg_in) {
    int e = blockIdx.x * 256 + threadIdx.x;
    if (e < N_EDGES) {
        atomicAdd(&deg_out[src[e]], 1.0f);
        atomicAdd(&deg_in[dst[e]], 1.0f);
    }
}

__global__ __launch_bounds__(256) void norm_kernel(float* __restrict__ deg, int n) {
    int i = blockIdx.x * 256 + threadIdx.x;
    if (i < n) deg[i] = rsqrtf(fmaxf(deg[i], 1.0f));
}

// ---------------- GEMM1: [N,256] @ [256,64] ----------------
// block = 256 threads, 16 rows per block. 3125 blocks exactly.
__global__ __launch_bounds__(256) void gemm1_kernel(const float* __restrict__ x,
                                                    const float* __restrict__ W1,
                                                    float* __restrict__ xw1) {
    __shared__ float xs[16][IN_FEATS];   // 16 KiB
    const int tid = threadIdx.x;
    const int n0 = blockIdx.x * 16;

    const float4* xv = (const float4*)(x + (size_t)n0 * IN_FEATS);
    float4* xsv = (float4*)&xs[0][0];
#pragma unroll
    for (int i = 0; i < 4; ++i) xsv[tid + i * 256] = xv[tid + i * 256];
    __syncthreads();

    const int h  = tid & 63;
    const int r0 = (tid >> 6) * 4;
    float a0 = 0.f, a1 = 0.f, a2 = 0.f, a3 = 0.f;
#pragma unroll 4
    for (int k = 0; k < IN_FEATS; ++k) {
        float w = W1[k * HIDDEN + h];
        a0 += xs[r0 + 0][k] * w;
        a1 += xs[r0 + 1][k] * w;
        a2 += xs[r0 + 2][k] * w;
        a3 += xs[r0 + 3][k] * w;
    }
    size_t base = (size_t)n0 * HIDDEN + h;
    xw1[base + (size_t)(r0 + 0) * HIDDEN] = a0;
    xw1[base + (size_t)(r0 + 1) * HIDDEN] = a1;
    xw1[base + (size_t)(r0 + 2) * HIDDEN] = a2;
    xw1[base + (size_t)(r0 + 3) * HIDDEN] = a3;
}

// ---------------- GEMM2: [N,64] @ [64,32] ----------------
// block = 256 threads, 8 rows per block. 6250 blocks exactly.
__global__ __launch_bounds__(256) void gemm2_kernel(const float* __restrict__ g1,
                                                    const float* __restrict__ W2,
                                                    float* __restrict__ xw2) {
    __shared__ float gs[8][HIDDEN];         // 2 KiB
    __shared__ float ws[HIDDEN * OUTF];     // 8 KiB
    const int tid = threadIdx.x;
    const int n0 = blockIdx.x * 8;

#pragma unroll
    for (int i = 0; i < 8; ++i) ws[tid + i * 256] = W2[tid + i * 256];
    const float4* gv = (const float4*)(g1 + (size_t)n0 * HIDDEN);
    if (tid < 128) ((float4*)&gs[0][0])[tid] = gv[tid];
    __syncthreads();

    const int o = tid & 31;
    const int r = tid >> 5;
    float acc = 0.f;
#pragma unroll
    for (int k = 0; k < HIDDEN; ++k) acc += gs[r][k] * ws[k * OUTF + o];
    xw2[(size_t)(n0 + r) * OUTF + o] = acc;
}

// ---------------- edge scatter, 64 feats (16 threads/edge, float4) ----------------
__global__ __launch_bounds__(256) void scatter64_kernel(const int* __restrict__ src,
                                                        const int* __restrict__ dst,
                                                        const float* __restrict__ norm_out,
                                                        const float* __restrict__ xw,
                                                        float* __restrict__ agg) {
    int gid = blockIdx.x * 256 + threadIdx.x;     // E*16 = 12.8M threads exactly
    int e  = gid >> 4;
    int f4 = gid & 15;
    int s = src[e], d = dst[e];
    float no = norm_out[s];
    float4 v = ((const float4*)(xw + (size_t)s * 64))[f4];
    float* ap = agg + (size_t)d * 64 + f4 * 4;
    atomicAdd(ap + 0, v.x * no);
    atomicAdd(ap + 1, v.y * no);
    atomicAdd(ap + 2, v.z * no);
    atomicAdd(ap + 3, v.w * no);
}

// ---------------- edge scatter, 32 feats (8 threads/edge, float4) ----------------
__global__ __launch_bounds__(256) void scatter32_kernel(const int* __restrict__ src,
                                                        const int* __restrict__ dst,
                                                        const float* __restrict__ norm_out,
                                                        const float* __restrict__ xw,
                                                        float* __restrict__ agg) {
    int gid = blockIdx.x * 256 + threadIdx.x;     // E*8 = 6.4M threads exactly
    int e  = gid >> 3;
    int f4 = gid & 7;
    int s = src[e], d = dst[e];
    float no = norm_out[s];
    float4 v = ((const float4*)(xw + (size_t)s * 32))[f4];
    float* ap = agg + (size_t)d * 32 + f4 * 4;
    atomicAdd(ap + 0, v.x * no);
    atomicAdd(ap + 1, v.y * no);
    atomicAdd(ap + 2, v.z * no);
    atomicAdd(ap + 3, v.w * no);
}

// ---------------- norm_in * agg + b, relu (in place) ----------------
__global__ __launch_bounds__(256) void finish_kernel(float* __restrict__ agg,
                                                     const float* __restrict__ norm_in,
                                                     const float* __restrict__ b,
                                                     int log2f, int total) {
    int i = blockIdx.x * 256 + threadIdx.x;
    if (i < total) {
        int n = i >> log2f;
        int h = i & ((1 << log2f) - 1);
        float v = agg[i] * norm_in[n] + b[h];
        agg[i] = fmaxf(v, 0.f);
    }
}

// ---------------- final: out[o] = sum_n g2[n,o]*fc_w[n] + fc_b ----------------
__global__ __launch_bounds__(32) void init_out_kernel(float* __restrict__ out,
                                                      const float* __restrict__ fc_b) {
    out[threadIdx.x] = fc_b[0];
}

__global__ __launch_bounds__(256) void reduce_kernel(const float* __restrict__ g2,
                                                     const float* __restrict__ fc_w,
                                                     float* __restrict__ out) {
    __shared__ float s[OUTF];
    const int tid = threadIdx.x;
    if (tid < OUTF) s[tid] = 0.f;
    __syncthreads();

    const int f4 = tid & 7;          // which float4 of the 32 feats
    int n = blockIdx.x * 32 + (tid >> 3);
    const int stride = gridDim.x * 32;
    float ax = 0.f, ay = 0.f, az = 0.f, aw = 0.f;
    for (; n < N_NODES; n += stride) {
        float w = fc_w[n];
        float4 g = ((const float4*)(g2 + (size_t)n * OUTF))[f4];
        ax += g.x * w; ay += g.y * w; az += g.z * w; aw += g.w * w;
    }
    atomicAdd(&s[f4 * 4 + 0], ax);
    atomicAdd(&s[f4 * 4 + 1], ay);
    atomicAdd(&s[f4 * 4 + 2], az);
    atomicAdd(&s[f4 * 4 + 3], aw);
    __syncthreads();
    if (tid < OUTF) atomicAdd(&out[tid], s[tid]);
}

extern "C" void kernel_launch(void* const* d_in, const int* in_sizes, int n_in,
                              void* d_out, int out_size, void* d_ws, size_t ws_size,
                              hipStream_t stream) {
    const float* x    = (const float*)d_in[0];
    const int*   src  = (const int*)d_in[1];
    const int*   dst  = (const int*)d_in[2];
    const float* W1   = (const float*)d_in[3];
    const float* b1   = (const float*)d_in[4];
    const float* W2   = (const float*)d_in[5];
    const float* b2   = (const float*)d_in[6];
    const float* fc_w = (const float*)d_in[7];
    const float* fc_b = (const float*)d_in[8];
    float* out = (float*)d_out;

    float* ws = (float*)d_ws;
    float* deg_out = ws;                        // [50000]  -> becomes norm_out
    float* deg_in  = ws + N_NODES;              // [50000]  -> becomes norm_in
    float* xw1     = ws + 2 * N_NODES;          // [50000*64]
    float* agg1    = xw1 + (size_t)N_NODES * HIDDEN;   // [50000*64] -> g1
    float* xw2     = agg1 + (size_t)N_NODES * HIDDEN;  // [50000*32]
    float* agg2    = xw2 + (size_t)N_NODES * OUTF;     // [50000*32] -> g2

    // zero accumulators (every call — graph replays must be deterministic)
    hipMemsetAsync(deg_out, 0, 2 * N_NODES * sizeof(float), stream);
    hipMemsetAsync(agg1, 0, (size_t)N_NODES * HIDDEN * sizeof(float), stream);
    hipMemsetAsync(agg2, 0, (size_t)N_NODES * OUTF * sizeof(float), stream);

    // degrees + norms
    deg_kernel<<<(N_EDGES + 255) / 256, 256, 0, stream>>>(src, dst, deg_out, deg_in);
    norm_kernel<<<(2 * N_NODES + 255) / 256, 256, 0, stream>>>(deg_out, 2 * N_NODES);

    // layer 1
    gemm1_kernel<<<N_NODES / 16, 256, 0, stream>>>(x, W1, xw1);
    scatter64_kernel<<<(N_EDGES * 16) / 256, 256, 0, stream>>>(src, dst, deg_out, xw1, agg1);
    finish_kernel<<<(N_NODES * HIDDEN + 255) / 256, 256, 0, stream>>>(agg1, deg_in, b1, 6,
                                                                      N_NODES * HIDDEN);

    // layer 2
    gemm2_kernel<<<N_NODES / 8, 256, 0, stream>>>(agg1, W2, xw2);
    scatter32_kernel<<<(N_EDGES * 8) / 256, 256, 0, stream>>>(src, dst, deg_out, xw2, agg2);
    finish_kernel<<<(N_NODES * OUTF + 255) / 256, 256, 0, stream>>>(agg2, deg_in, b2, 5,
                                                                    N_NODES * OUTF);

    // final projection
    init_out_kernel<<<1, 32, 0, stream>>>(out, fc_b);
    reduce_kernel<<<512, 256, 0, stream>>>(agg2, fc_w, out);
}

// Round 2
// 261.651 us; speedup vs baseline: 4.4246x; 4.4246x over previous
//
#include <hip/hip_runtime.h>

#define N_NODES 50000
#define N_EDGES 800000
#define IN_FEATS 256
#define HIDDEN 64
#define OUTF 32
#define SCAN_BLOCKS 196   // ceil(50000/256)

// ---------------- degree histogram (int) ----------------
__global__ __launch_bounds__(256) void deg_count_kernel(const int* __restrict__ src,
                                                        const int* __restrict__ dst,
                                                        int* __restrict__ deg_out_i,
                                                        int* __restrict__ deg_in_i) {
    int e = blockIdx.x * 256 + threadIdx.x;
    if (e < N_EDGES) {
        atomicAdd(&deg_out_i[src[e]], 1);
        atomicAdd(&deg_in_i[dst[e]], 1);
    }
}

// ---------------- norms from int degrees ----------------
__global__ __launch_bounds__(256) void norms_kernel(const int* __restrict__ deg_out_i,
                                                    const int* __restrict__ deg_in_i,
                                                    float* __restrict__ norm_out,
                                                    float* __restrict__ norm_in) {
    int i = blockIdx.x * 256 + threadIdx.x;
    if (i < N_NODES) {
        norm_out[i] = rsqrtf(fmaxf((float)deg_out_i[i], 1.0f));
        norm_in[i]  = rsqrtf(fmaxf((float)deg_in_i[i], 1.0f));
    }
}

// ---------------- exclusive scan of deg_in (3 kernels) ----------------
__global__ __launch_bounds__(256) void scan1_kernel(const int* __restrict__ cnt,
                                                    int* __restrict__ row_start,
                                                    int* __restrict__ block_sums) {
    __shared__ int s[256];
    int i = blockIdx.x * 256 + threadIdx.x;
    int v = (i < N_NODES) ? cnt[i] : 0;
    s[threadIdx.x] = v;
    __syncthreads();
#pragma unroll
    for (int off = 1; off < 256; off <<= 1) {
        int t = (threadIdx.x >= off) ? s[threadIdx.x - off] : 0;
        __syncthreads();
        s[threadIdx.x] += t;
        __syncthreads();
    }
    if (i < N_NODES) row_start[i] = s[threadIdx.x] - v;   // exclusive
    if (threadIdx.x == 255) block_sums[blockIdx.x] = s[255];
}

__global__ __launch_bounds__(256) void scan2_kernel(int* __restrict__ block_sums) {
    __shared__ int s[256];
    int v = (threadIdx.x < SCAN_BLOCKS) ? block_sums[threadIdx.x] : 0;
    s[threadIdx.x] = v;
    __syncthreads();
#pragma unroll
    for (int off = 1; off < 256; off <<= 1) {
        int t = (threadIdx.x >= off) ? s[threadIdx.x - off] : 0;
        __syncthreads();
        s[threadIdx.x] += t;
        __syncthreads();
    }
    if (threadIdx.x < SCAN_BLOCKS) block_sums[threadIdx.x] = s[threadIdx.x] - v;
}

__global__ __launch_bounds__(256) void scan3_kernel(int* __restrict__ row_start,
                                                    const int* __restrict__ block_sums) {
    int i = blockIdx.x * 256 + threadIdx.x;
    if (i < N_NODES) row_start[i] += block_sums[blockIdx.x];
    if (i == 0) row_start[N_NODES] = N_EDGES;
}

// ---------------- CSR fill: bucket src ids by dst ----------------
__global__ __launch_bounds__(256) void fill_csr_kernel(const int* __restrict__ src,
                                                       const int* __restrict__ dst,
                                                       const int* __restrict__ row_start,
                                                       int* __restrict__ cursor,
                                                       int* __restrict__ csr_src) {
    int e = blockIdx.x * 256 + threadIdx.x;
    if (e < N_EDGES) {
        int d = dst[e];
        int pos = atomicAdd(&cursor[d], 1);
        csr_src[row_start[d] + pos] = src[e];
    }
}

// ---------------- GEMM1: xw1[n] = (x[n] @ W1) * norm_out[n] ----------------
__global__ __launch_bounds__(256) void gemm1_kernel(const float* __restrict__ x,
                                                    const float* __restrict__ W1,
                                                    const float* __restrict__ norm_out,
                                                    float* __restrict__ xw1) {
    __shared__ float xs[16][IN_FEATS];   // 16 KiB
    const int tid = threadIdx.x;
    const int n0 = blockIdx.x * 16;

    const float4* xv = (const float4*)(x + (size_t)n0 * IN_FEATS);
    float4* xsv = (float4*)&xs[0][0];
#pragma unroll
    for (int i = 0; i < 4; ++i) xsv[tid + i * 256] = xv[tid + i * 256];
    __syncthreads();

    const int h  = tid & 63;
    const int r0 = (tid >> 6) * 4;
    float a0 = 0.f, a1 = 0.f, a2 = 0.f, a3 = 0.f;
#pragma unroll 4
    for (int k = 0; k < IN_FEATS; ++k) {
        float w = W1[k * HIDDEN + h];
        a0 += xs[r0 + 0][k] * w;
        a1 += xs[r0 + 1][k] * w;
        a2 += xs[r0 + 2][k] * w;
        a3 += xs[r0 + 3][k] * w;
    }
    size_t base = (size_t)n0 * HIDDEN + h;
    xw1[base + (size_t)(r0 + 0) * HIDDEN] = a0 * norm_out[n0 + r0 + 0];
    xw1[base + (size_t)(r0 + 1) * HIDDEN] = a1 * norm_out[n0 + r0 + 1];
    xw1[base + (size_t)(r0 + 2) * HIDDEN] = a2 * norm_out[n0 + r0 + 2];
    xw1[base + (size_t)(r0 + 3) * HIDDEN] = a3 * norm_out[n0 + r0 + 3];
}

// ---------------- GEMM2: xw2[n] = (g1[n] @ W2) * norm_out[n] ----------------
__global__ __launch_bounds__(256) void gemm2_kernel(const float* __restrict__ g1,
                                                    const float* __restrict__ W2,
                                                    const float* __restrict__ norm_out,
                                                    float* __restrict__ xw2) {
    __shared__ float gs[8][HIDDEN];         // 2 KiB
    __shared__ float ws[HIDDEN * OUTF];     // 8 KiB
    const int tid = threadIdx.x;
    const int n0 = blockIdx.x * 8;

#pragma unroll
    for (int i = 0; i < 8; ++i) ws[tid + i * 256] = W2[tid + i * 256];
    const float4* gv = (const float4*)(g1 + (size_t)n0 * HIDDEN);
    if (tid < 128) ((float4*)&gs[0][0])[tid] = gv[tid];
    __syncthreads();

    const int o = tid & 31;
    const int r = tid >> 5;
    float acc = 0.f;
#pragma unroll
    for (int k = 0; k < HIDDEN; ++k) acc += gs[r][k] * ws[k * OUTF + o];
    xw2[(size_t)(n0 + r) * OUTF + o] = acc * norm_out[n0 + r];
}

// ---------------- gather 64 feats: one wave per node ----------------
__global__ __launch_bounds__(256) void gather64_kernel(const int* __restrict__ row_start,
                                                       const int* __restrict__ csr_src,
                                                       const float* __restrict__ xw,
                                                       const float* __restrict__ norm_in,
                                                       const float* __restrict__ b,
                                                       float* __restrict__ g) {
    int n = blockIdx.x * 4 + (threadIdx.x >> 6);
    if (n >= N_NODES) return;
    int lane = threadIdx.x & 63;
    int beg = row_start[n], end = row_start[n + 1];
    float acc = 0.f;
    int i = beg;
    for (; i + 4 <= end; i += 4) {
        int s0 = csr_src[i + 0], s1 = csr_src[i + 1];
        int s2 = csr_src[i + 2], s3 = csr_src[i + 3];
        float v0 = xw[(size_t)s0 * 64 + lane];
        float v1 = xw[(size_t)s1 * 64 + lane];
        float v2 = xw[(size_t)s2 * 64 + lane];
        float v3 = xw[(size_t)s3 * 64 + lane];
        acc += (v0 + v1) + (v2 + v3);
    }
    for (; i < end; ++i) acc += xw[(size_t)csr_src[i] * 64 + lane];
    g[(size_t)n * 64 + lane] = fmaxf(acc * norm_in[n] + b[lane], 0.f);
}

// ---------------- gather 32 feats: half-wave per node ----------------
__global__ __launch_bounds__(256) void gather32_kernel(const int* __restrict__ row_start,
                                                       const int* __restrict__ csr_src,
                                                       const float* __restrict__ xw,
                                                       const float* __restrict__ norm_in,
                                                       const float* __restrict__ b,
                                                       float* __restrict__ g) {
    int n = blockIdx.x * 8 + (threadIdx.x >> 5);
    if (n >= N_NODES) return;
    int lane = threadIdx.x & 31;
    int beg = row_start[n], end = row_start[n + 1];
    float acc = 0.f;
    int i = beg;
    for (; i + 4 <= end; i += 4) {
        int s0 = csr_src[i + 0], s1 = csr_src[i + 1];
        int s2 = csr_src[i + 2], s3 = csr_src[i + 3];
        float v0 = xw[(size_t)s0 * 32 + lane];
        float v1 = xw[(size_t)s1 * 32 + lane];
        float v2 = xw[(size_t)s2 * 32 + lane];
        float v3 = xw[(size_t)s3 * 32 + lane];
        acc += (v0 + v1) + (v2 + v3);
    }
    for (; i < end; ++i) acc += xw[(size_t)csr_src[i] * 32 + lane];
    g[(size_t)n * 32 + lane] = fmaxf(acc * norm_in[n] + b[lane], 0.f);
}

// ---------------- final: out[o] = sum_n g2[n,o]*fc_w[n] + fc_b ----------------
__global__ __launch_bounds__(32) void init_out_kernel(float* __restrict__ out,
                                                      const float* __restrict__ fc_b) {
    out[threadIdx.x] = fc_b[0];
}

__global__ __launch_bounds__(256) void reduce_kernel(const float* __restrict__ g2,
                                                     const float* __restrict__ fc_w,
                                                     float* __restrict__ out) {
    __shared__ float s[OUTF];
    const int tid = threadIdx.x;
    if (tid < OUTF) s[tid] = 0.f;
    __syncthreads();

    const int f4 = tid & 7;
    int n = blockIdx.x * 32 + (tid >> 3);
    const int stride = gridDim.x * 32;
    float ax = 0.f, ay = 0.f, az = 0.f, aw = 0.f;
    for (; n < N_NODES; n += stride) {
        float w = fc_w[n];
        float4 g = ((const float4*)(g2 + (size_t)n * OUTF))[f4];
        ax += g.x * w; ay += g.y * w; az += g.z * w; aw += g.w * w;
    }
    atomicAdd(&s[f4 * 4 + 0], ax);
    atomicAdd(&s[f4 * 4 + 1], ay);
    atomicAdd(&s[f4 * 4 + 2], az);
    atomicAdd(&s[f4 * 4 + 3], aw);
    __syncthreads();
    if (tid < OUTF) atomicAdd(&out[tid], s[tid]);
}

extern "C" void kernel_launch(void* const* d_in, const int* in_sizes, int n_in,
                              void* d_out, int out_size, void* d_ws, size_t ws_size,
                              hipStream_t stream) {
    const float* x    = (const float*)d_in[0];
    const int*   src  = (const int*)d_in[1];
    const int*   dst  = (const int*)d_in[2];
    const float* W1   = (const float*)d_in[3];
    const float* b1   = (const float*)d_in[4];
    const float* W2   = (const float*)d_in[5];
    const float* b2   = (const float*)d_in[6];
    const float* fc_w = (const float*)d_in[7];
    const float* fc_b = (const float*)d_in[8];
    float* out = (float*)d_out;

    // ---- workspace layout ----
    int* ip = (int*)d_ws;
    int* deg_out_i  = ip;                 // 50000
    int* deg_in_i   = ip + 50000;         // 50000 (contiguous with deg_out_i for one memset)
    int* row_start  = ip + 100000;        // 50001
    int* cursor     = ip + 150001;        // 50000
    int* block_sums = ip + 200001;        // 256
    int* csr_src    = ip + 200257;        // 800000
    float* fp = (float*)(ip + 1000448);   // 16B-aligned float region
    float* xw_buf   = fp;                 // 3.2M floats (xw1, then reused as xw2)
    float* g_buf    = fp + 3200000;       // 3.2M floats (g1, then reused as g2)
    float* norm_out = fp + 6400000;       // 50000
    float* norm_in  = fp + 6450000;       // 50000

    // ---- zero the counters (every call: graph replays must be correct) ----
    hipMemsetAsync(deg_out_i, 0, 100000 * sizeof(int), stream);
    hipMemsetAsync(cursor, 0, 50000 * sizeof(int), stream);

    // ---- CSR build ----
    deg_count_kernel<<<(N_EDGES + 255) / 256, 256, 0, stream>>>(src, dst, deg_out_i, deg_in_i);
    norms_kernel<<<SCAN_BLOCKS, 256, 0, stream>>>(deg_out_i, deg_in_i, norm_out, norm_in);
    scan1_kernel<<<SCAN_BLOCKS, 256, 0, stream>>>(deg_in_i, row_start, block_sums);
    scan2_kernel<<<1, 256, 0, stream>>>(block_sums);
    scan3_kernel<<<SCAN_BLOCKS, 256, 0, stream>>>(row_start, block_sums);
    fill_csr_kernel<<<(N_EDGES + 255) / 256, 256, 0, stream>>>(src, dst, row_start, cursor, csr_src);

    // ---- layer 1 ----
    gemm1_kernel<<<N_NODES / 16, 256, 0, stream>>>(x, W1, norm_out, xw_buf);
    gather64_kernel<<<(N_NODES + 3) / 4, 256, 0, stream>>>(row_start, csr_src, xw_buf,
                                                           norm_in, b1, g_buf);

    // ---- layer 2 (xw2 reuses xw_buf; g2 reuses g_buf) ----
    gemm2_kernel<<<N_NODES / 8, 256, 0, stream>>>(g_buf, W2, norm_out, xw_buf);
    gather32_kernel<<<(N_NODES + 7) / 8, 256, 0, stream>>>(row_start, csr_src, xw_buf,
                                                           norm_in, b2, g_buf);

    // ---- final projection ----
    init_out_kernel<<<1, 32, 0, stream>>>(out, fc_b);
    reduce_kernel<<<512, 256, 0, stream>>>(g_buf, fc_w, out);
}